// Round 6
// baseline (713.282 us; speedup 1.0000x reference)
//
#include <hip/hip_runtime.h>
#include <cstdint>
#include <climits>

#define N 8192
#define D 64
#define H 128
#define O 64
#define KNB 16
#define NE (N*KNB)        // 131072
#define ETOT (NE + N)     // 139264
#define OUT0 (N*D)        // 524288
#define NSPL 32           // j-splits for scan kernels
#define JSPAN 256         // j's per split (N/NSPL)
#define CAP 96            // candidate buffer per query

__device__ __forceinline__ float bf2f(unsigned short u){
    union { unsigned int u; float f; } v; v.u = ((unsigned int)u) << 16; return v.f;
}
__device__ __forceinline__ unsigned short f2bf(float f){
    union { float f; unsigned int u; } v; v.f = f;
    unsigned int r = v.u + 0x7FFFu + ((v.u >> 16) & 1u);   // RNE
    return (unsigned short)(r >> 16);
}

// Pin a float4 array's components into VGPRs: the empty asm's outputs are
// non-rematerializable defs, so the compiler CANNOT sink/remat the loads
// into the loop (round-5 post-mortem: scheduler kept VGPR_Count=40 and
// re-loaded the 64-VGPR query row from global EVERY j-iteration with
// per-lane addresses — the launch_bounds budget alone didn't stop it).
#define PIN4(v) asm volatile("" : "+v"((v).x), "+v"((v).y), "+v"((v).z), "+v"((v).w))

// ---------------- dtype probe: 1=bf16 inputs, 0=fp32 inputs ----------------
__global__ void k_probe(const unsigned short* __restrict__ x, int* __restrict__ flag){
    __shared__ int cnt;
    if (threadIdx.x == 0) cnt = 0;
    __syncthreads();
    unsigned short u = x[2*threadIdx.x];
    int e = (u >> 7) & 0xFF;
    int ok = (u == 0) || (e >= 0x60 && e <= 0x85);
    unsigned long long m = __ballot(ok);
    if ((threadIdx.x & 63) == 0) atomicAdd(&cnt, __popcll(m));
    __syncthreads();
    if (threadIdx.x == 0) *flag = (cnt >= 128) ? 1 : 0;
}

// ---------------- generic input convert -> fp32 ----------------
__global__ void k_cvt(const void* __restrict__ src, float* __restrict__ dst,
                      int n, const int* __restrict__ flag){
    int i = blockIdx.x*256 + threadIdx.x;
    if (i >= n) return;
    if (*flag) dst[i] = bf2f(((const unsigned short*)src)[i]);
    else       dst[i] = ((const float*)src)[i];
}

// ---------------- row norms: EXACT numpy fp32 pairwise semantics ----------------
__global__ void k_prep(const float* __restrict__ xf, float* __restrict__ nrmf){
    int i = blockIdx.x*64 + threadIdx.x;
    const float* xr = xf + i*D;
    float r[8];
    #pragma unroll
    for (int q = 0; q < 8; ++q) r[q] = __fmul_rn(xr[q], xr[q]);
    #pragma unroll
    for (int b = 8; b < 64; b += 8)
        #pragma unroll
        for (int q = 0; q < 8; ++q)
            r[q] = __fadd_rn(r[q], __fmul_rn(xr[b+q], xr[b+q]));
    float s = __fadd_rn(__fadd_rn(__fadd_rn(r[0],r[1]), __fadd_rn(r[2],r[3])),
                        __fadd_rn(__fadd_rn(r[4],r[5]), __fadd_rn(r[6],r[7])));
    nrmf[i] = __fsqrt_rn(s);
}

// =====================================================================
// Two-pass exact top-k.
// (A) cheap scan keeping per-chunk top-2 VALUES, (B) v_i = 16th largest
// of the 64-value union (subset of row i's sims -> provably <= true 16th
// largest), (C) rescan with fixed threshold v_i appending exact (s,j)
// candidates (superset of the true top-16), (D) exact (value desc,
// idx asc) selection among candidates. All sim values use the verified
// sequential fp32 FMA chain:
//   a = fma-chain k=0..63; den = fadd(fmul(ni,nj),1e-8); s = fdiv(a,den).
//
// Register residency: SGPR=96 shows the wave-uniform j-row IS scalarized
// (s_load_dwordx4 chains) — good. The per-lane query row xi4[16] must be
// PINNED (PIN4) or the scheduler remats its loads into the loop
// (round-5: VGPR_Count=40 < the 64 VGPRs xi4 needs, dur 3x floor).
// __launch_bounds__(256, 2): 256-VGPR budget so the pinned ~110-VGPR
// working set has headroom. Round-1 lesson: never cap below working set
// ((512,4) forced 64-VGPR cap -> 22 GB scratch).
// =====================================================================

// ---- pass A: per-lane query, wave-uniform j, keep chunk top-2 values ----
__global__ __launch_bounds__(256, 2) void k_scan2(const float* __restrict__ xf,
                                                  const float* __restrict__ nrmf,
                                                  float* __restrict__ chunk2){
    int tid = threadIdx.x;
    int grp = blockIdx.x & 31;        // 32 query groups of 256
    int split = blockIdx.x >> 5;      // 32 j-splits
    int i = grp*256 + tid;
    int jbase = split*JSPAN;

    const float4* xip = (const float4*)(xf + (size_t)i*D);
    float4 xi4[16];
    #pragma unroll
    for (int c = 0; c < 16; ++c) xi4[c] = xip[c];
    #pragma unroll
    for (int c = 0; c < 16; ++c) PIN4(xi4[c]);
    float ni = nrmf[i];
    asm volatile("" : "+v"(ni));

    float v0 = -3.0e38f, v1 = -3.0e38f;   // chunk top-2 values

    for (int jj = 0; jj < JSPAN; ++jj){
        int j = jbase + jj;                         // wave-uniform
        const float4* A = (const float4*)(xf + (size_t)j*D);
        float nj = nrmf[j];
        float a = 0.0f;
        #pragma unroll
        for (int c = 0; c < 16; ++c){
            float4 b = A[c]; float4 xa = xi4[c];    // b uniform across lanes
            a = __fmaf_rn(b.x, xa.x, a);
            a = __fmaf_rn(b.y, xa.y, a);
            a = __fmaf_rn(b.z, xa.z, a);
            a = __fmaf_rn(b.w, xa.w, a);
        }
        float den = __fadd_rn(__fmul_rn(ni, nj), 1e-8f);
        float thr = v1*den;
        // conservative prefilter (margin >> fdiv rounding), exact recheck
        if (j != i && a > __fmaf_rn(fabsf(thr), -1e-6f, thr)){
            float s0 = __fdiv_rn(a, den);
            if (s0 > v1){
                if (s0 > v0){ v1 = v0; v0 = s0; } else v1 = s0;
            }
        }
    }
    chunk2[(size_t)i*64 + split*2    ] = v0;
    chunk2[(size_t)i*64 + split*2 + 1] = v1;
}

// ---- v_i = 16th largest of the 64 chunk-top-2 values (subset bound) ----
__global__ void k_vsel(const float* __restrict__ chunk2, float* __restrict__ vthr){
    int i = blockIdx.x*256 + threadIdx.x;
    const float* c = chunk2 + (size_t)i*64;
    float lv[16];
    #pragma unroll
    for (int r = 0; r < 16; ++r) lv[r] = -3.0e38f;
    for (int k = 0; k < 64; ++k){
        float s = c[k];
        if (s > lv[15]){
            lv[15] = s;
            #pragma unroll
            for (int r = 15; r > 0; --r){
                if (lv[r] > lv[r-1]){ float tv = lv[r]; lv[r] = lv[r-1]; lv[r-1] = tv; }
            }
        }
    }
    vthr[i] = lv[15];
}

__global__ void k_zero(int* __restrict__ cnt){
    int i = blockIdx.x*256 + threadIdx.x;
    if (i < N) cnt[i] = 0;
}

// ---- pass B: rescan with fixed threshold, append exact candidates ----
__global__ __launch_bounds__(256, 2) void k_filter(const float* __restrict__ xf,
                                                   const float* __restrict__ nrmf,
                                                   const float* __restrict__ vthr,
                                                   int* __restrict__ cnt,
                                                   float* __restrict__ candV,
                                                   int* __restrict__ candI){
    int tid = threadIdx.x;
    int grp = blockIdx.x & 31;
    int split = blockIdx.x >> 5;
    int i = grp*256 + tid;
    int jbase = split*JSPAN;

    const float4* xip = (const float4*)(xf + (size_t)i*D);
    float4 xi4[16];
    #pragma unroll
    for (int c = 0; c < 16; ++c) xi4[c] = xip[c];
    #pragma unroll
    for (int c = 0; c < 16; ++c) PIN4(xi4[c]);
    float ni = nrmf[i];
    float v = vthr[i];
    asm volatile("" : "+v"(ni), "+v"(v));

    for (int jj = 0; jj < JSPAN; ++jj){
        int j = jbase + jj;
        const float4* A = (const float4*)(xf + (size_t)j*D);
        float nj = nrmf[j];
        float a = 0.0f;
        #pragma unroll
        for (int c = 0; c < 16; ++c){
            float4 b = A[c]; float4 xa = xi4[c];
            a = __fmaf_rn(b.x, xa.x, a);
            a = __fmaf_rn(b.y, xa.y, a);
            a = __fmaf_rn(b.z, xa.z, a);
            a = __fmaf_rn(b.w, xa.w, a);
        }
        float den = __fadd_rn(__fmul_rn(ni, nj), 1e-8f);
        float t = v*den;
        // conservative: keep every j with s >= v (den > 0 always)
        if (j != i && a >= __fmaf_rn(fabsf(t), -1e-6f, t)){
            float s0 = __fdiv_rn(a, den);
            if (s0 >= v){
                int slot = atomicAdd(&cnt[i], 1);
                if (slot < CAP){
                    candV[(size_t)i*CAP + slot] = s0;
                    candI[(size_t)i*CAP + slot] = j;
                }
            }
        }
    }
}

// ---- exact top-16 among candidates; serial exact fallback on overflow ----
__global__ __launch_bounds__(64) void k_select(const float* __restrict__ xf,
                                               const float* __restrict__ nrmf,
                                               const int* __restrict__ cnt,
                                               const float* __restrict__ candV,
                                               const int* __restrict__ candI,
                                               int* __restrict__ topIdx,
                                               float* __restrict__ ewArr){
    __shared__ float sv[64*97];   // stride 97: bank-conflict-free per-lane rows
    __shared__ int   si[64*97];
    int t = threadIdx.x;
    int i = blockIdx.x*64 + t;
    int c = cnt[i];
    bool ovf = (c > CAP);
    int cc = ovf ? 0 : c;
    for (int k = 0; k < CAP; ++k){
        bool in = (k < cc);
        sv[t*97 + k] = in ? candV[(size_t)i*CAP + k] : -3.0e38f;
        si[t*97 + k] = in ? candI[(size_t)i*CAP + k] : INT_MAX;
    }
    if (!ovf){
        // guaranteed cc >= 16 (all j with s >= v stored; >=16 such exist)
        #pragma unroll 1
        for (int sel = 0; sel < KNB; ++sel){
            float bv = -3.0e38f; int bi = INT_MAX; int bk = 0;
            for (int k = 0; k < CAP; ++k){
                float vv = sv[t*97 + k]; int id = si[t*97 + k];
                if (vv > bv || (vv == bv && id < bi)){ bv = vv; bi = id; bk = k; }
            }
            sv[t*97 + bk] = -3.0e38f;
            si[t*97 + bk] = INT_MAX;
            topIdx[i*KNB + sel] = bi;
            ewArr [i*KNB + sel] = (bv > 0.5f) ? bv : 0.0f;
        }
    } else {
        // exact serial full scan (expected never on this data; correctness net)
        const float4* xip = (const float4*)(xf + (size_t)i*D);
        float4 xi4[16];
        #pragma unroll
        for (int cc2 = 0; cc2 < 16; ++cc2) xi4[cc2] = xip[cc2];
        float ni = nrmf[i];
        float lv[16]; int li[16];
        #pragma unroll
        for (int r = 0; r < 16; ++r){ lv[r] = -3.0e38f; li[r] = INT_MAX; }
        for (int j = 0; j < N; ++j){
            if (j == i) continue;
            const float4* A = (const float4*)(xf + (size_t)j*D);
            float a = 0.0f;
            #pragma unroll
            for (int cc2 = 0; cc2 < 16; ++cc2){
                float4 b = A[cc2]; float4 xa = xi4[cc2];
                a = __fmaf_rn(b.x, xa.x, a);
                a = __fmaf_rn(b.y, xa.y, a);
                a = __fmaf_rn(b.z, xa.z, a);
                a = __fmaf_rn(b.w, xa.w, a);
            }
            float den = __fadd_rn(__fmul_rn(ni, nrmf[j]), 1e-8f);
            float s0 = __fdiv_rn(a, den);
            if (s0 > lv[15]){   // strict >: ascending j scan == idx-asc ties
                lv[15] = s0; li[15] = j;
                #pragma unroll
                for (int r = 15; r > 0; --r){
                    if (lv[r] > lv[r-1]){
                        float tv = lv[r]; lv[r] = lv[r-1]; lv[r-1] = tv;
                        int ti = li[r]; li[r] = li[r-1]; li[r-1] = ti;
                    }
                }
            }
        }
        #pragma unroll
        for (int sel = 0; sel < KNB; ++sel){
            topIdx[i*KNB + sel] = li[sel];
            ewArr [i*KNB + sel] = (lv[sel] > 0.5f) ? lv[sel] : 0.0f;
        }
    }
}

// ---------------- degree / dinv ----------------
__global__ void k_deg_init(double* __restrict__ degD){
    int j = blockIdx.x*blockDim.x + threadIdx.x;
    if (j < N) degD[j] = 2.0;
}
__global__ void k_deg_scatter(const int* __restrict__ topIdx, const float* __restrict__ ewArr,
                              double* __restrict__ degD){
    int e = blockIdx.x*blockDim.x + threadIdx.x;
    if (e < NE){
        float w = ewArr[e];
        if (w > 0.0f) atomicAdd(&degD[topIdx[e]], (double)w);
    }
}
__global__ void k_dinv(const double* __restrict__ degD, float* __restrict__ dinv){
    int j = blockIdx.x*blockDim.x + threadIdx.x;
    if (j < N) dinv[j] = (float)(1.0 / sqrt(degD[j]));
}

// ---------------- dense matmuls ----------------
__global__ void k_gemm1(const float* __restrict__ xf, const float* __restrict__ W1,
                        float* __restrict__ h1){
    int id = blockIdx.x*256 + threadIdx.x;
    int i = id >> 7; int f = id & (H-1);
    const float* xr = xf + i*D;
    float acc = 0.f;
    #pragma unroll
    for (int k = 0; k < D; ++k) acc += xr[k] * W1[k*H + f];
    h1[id] = acc;
}
__global__ void k_gemm2(const float* __restrict__ z1, const float* __restrict__ W2,
                        float* __restrict__ h2){
    int id = blockIdx.x*256 + threadIdx.x;
    int i = id >> 6; int f = id & (O-1);
    const float* zr = z1 + i*H;
    float acc = 0.f;
    #pragma unroll
    for (int k = 0; k < H; ++k) acc += zr[k] * W2[k*O + f];
    h2[id] = acc;
}
__global__ void k_proj(const float* __restrict__ z2, const float* __restrict__ Wp,
                       const float* __restrict__ bp, float* __restrict__ z3){
    int id = blockIdx.x*256 + threadIdx.x;
    int i = id >> 6; int f = id & (D-1);
    const float* zr = z2 + i*O;
    float acc = bp[f];
    #pragma unroll
    for (int k = 0; k < O; ++k) acc += zr[k] * Wp[k*D + f];
    z3[id] = acc;
}

// ---------------- GCN aggregation ----------------
template<int F>
__global__ void k_agg_init(const float* __restrict__ h, const float* __restrict__ dinv,
                           float* __restrict__ agg){
    int id = blockIdx.x*256 + threadIdx.x;
    int j = id / F;
    float dj = dinv[j];
    agg[id] = 2.f * dj * dj * h[id];
}
template<int F>
__global__ void k_agg_scat(const int* __restrict__ topIdx, const float* __restrict__ ewArr,
                           const float* __restrict__ dinv, const float* __restrict__ h,
                           float* __restrict__ agg){
    int e = blockIdx.x; int f = threadIdx.x;
    float w = ewArr[e];
    if (w == 0.f) return;
    int s = e >> 4;
    int dn = topIdx[e];
    float c = dinv[s] * w * dinv[dn];
    atomicAdd(&agg[dn*F + f], c * h[s*F + f]);
}

// ---------------- bias + relu + layernorm ----------------
__global__ void k_post128(const float* __restrict__ agg, const float* __restrict__ b,
                          const float* __restrict__ g, const float* __restrict__ be,
                          float* __restrict__ z){
    __shared__ double s2[2];
    __shared__ double s3[2];
    int i = blockIdx.x; int f = threadIdx.x;
    float v = agg[i*H + f] + b[f];
    v = v > 0.f ? v : 0.f;
    int wid = f >> 6;
    double d = (double)v;
    for (int off = 32; off > 0; off >>= 1) d += __shfl_xor(d, off);
    if ((f & 63) == 0) s2[wid] = d;
    __syncthreads();
    double mu = (s2[0] + s2[1]) * (1.0/128.0);
    double dv = (double)v - mu;
    double qq = dv * dv;
    for (int off = 32; off > 0; off >>= 1) qq += __shfl_xor(qq, off);
    if ((f & 63) == 0) s3[wid] = qq;
    __syncthreads();
    double var = (s3[0] + s3[1]) * (1.0/128.0);
    double rs = 1.0 / sqrt(var + 1e-5);
    z[i*H + f] = (float)(dv * rs * (double)g[f] + (double)be[f]);
}
__global__ void k_post64(const float* __restrict__ agg, const float* __restrict__ b,
                         const float* __restrict__ g, const float* __restrict__ be,
                         float* __restrict__ z){
    int i = blockIdx.x; int f = threadIdx.x;
    float v = agg[i*O + f] + b[f];
    v = v > 0.f ? v : 0.f;
    double d = (double)v;
    for (int off = 32; off > 0; off >>= 1) d += __shfl_xor(d, off);
    double mu = d * (1.0/64.0);
    double dv = (double)v - mu;
    double qq = dv * dv;
    for (int off = 32; off > 0; off >>= 1) qq += __shfl_xor(qq, off);
    double var = qq * (1.0/64.0);
    double rs = 1.0 / sqrt(var + 1e-5);
    z[i*O + f] = (float)(dv * rs * (double)g[f] + (double)be[f]);
}

// ---------------- output stores (flag-branched dtype) ----------------
__global__ void k_store(const float* __restrict__ z3, void* __restrict__ outp,
                        const int* __restrict__ flag){
    int i = blockIdx.x*256 + threadIdx.x;
    float v = z3[i];
    if (*flag) ((unsigned short*)outp)[i] = f2bf(v);
    else       ((float*)outp)[i] = v;
}
__global__ void k_edges(const int* __restrict__ topIdx, const float* __restrict__ ewArr,
                        void* __restrict__ outp, const int* __restrict__ flag){
    int e = blockIdx.x*256 + threadIdx.x;
    if (e >= ETOT) return;
    int s, dn; float w;
    if (e < NE){ s = e >> 4; dn = topIdx[e]; w = ewArr[e]; }
    else       { s = e - NE; dn = s;        w = 1.0f; }
    if (*flag){
        unsigned short* o = (unsigned short*)outp;
        o[OUT0 + e]          = f2bf((float)s);
        o[OUT0 + ETOT + e]   = f2bf((float)dn);
        o[OUT0 + 2*ETOT + e] = f2bf(w);
    } else {
        float* o = (float*)outp;
        o[OUT0 + e]          = (float)s;
        o[OUT0 + ETOT + e]   = (float)dn;
        o[OUT0 + 2*ETOT + e] = w;
    }
}

extern "C" void kernel_launch(void* const* d_in, const int* in_sizes, int n_in,
                              void* d_out, int out_size, void* d_ws, size_t ws_size,
                              hipStream_t stream){
    char* ws = (char*)d_ws;
    int*    flag   = (int*)   (ws + 0);
    float*  w1f    = (float*) (ws + 4096);
    float*  b1f    = (float*) (ws + 36864);
    float*  g1f    = (float*) (ws + 37376);
    float*  be1f   = (float*) (ws + 37888);
    float*  w2f    = (float*) (ws + 38400);
    float*  b2f    = (float*) (ws + 71168);
    float*  g2f    = (float*) (ws + 71424);
    float*  be2f   = (float*) (ws + 71680);
    float*  wpf    = (float*) (ws + 71936);
    float*  bpf    = (float*) (ws + 88320);
    float*  xf     = (float*) (ws + 98304);      // 2 MB          -> 2195456
    float*  nrmf   = (float*) (ws + 2195456);    // 32 KB         -> 2228224
    int*    topIdx = (int*)   (ws + 2260992);    // 512 KB        -> 2785280
    float*  ewArr  = (float*) (ws + 2785280);    // 512 KB        -> 3309568
    double* degD   = (double*)(ws + 3309568);    // 64 KB         -> 3375104
    float*  dinv   = (float*) (ws + 3375104);    // 32 KB         -> 3407872
    float*  h1     = (float*) (ws + 3407872);    // 4 MB          -> 7602176
    float*  agg1   = (float*) (ws + 7602176);    // 4 MB          -> 11796480
    float*  z1     = (float*) (ws + 11796480);   // 4 MB          -> 15990784
    float*  h2     = h1;
    float*  agg2   = agg1;
    float*  z2     = z1;
    float*  z3     = h1;

    // topk scratch overlaps h1/agg1/z1-head (all dead until k_gemm1, which
    // launches after k_select completes).
    float* chunk2 = (float*)(ws + 3407872);                  // 8192*64*4 = 2 MB
    float* vthr   = (float*)(ws + 3407872 + 2097152);        // 32 KB
    int*   cntb   = (int*)  (ws + 3407872 + 2097152 + 32768);// 32 KB
    float* candV  = (float*)(ws + 3407872 + 2097152 + 65536);            // 3 MB
    int*   candI  = (int*)  (ws + 3407872 + 2097152 + 65536 + 3145728);  // 3 MB

    k_probe<<<1, 256, 0, stream>>>((const unsigned short*)d_in[0], flag);
    k_cvt<<<(N*D+255)/256, 256, 0, stream>>>(d_in[0], xf,  N*D, flag);
    k_cvt<<<(D*H+255)/256, 256, 0, stream>>>(d_in[1], w1f, D*H, flag);
    k_cvt<<<1, 256, 0, stream>>>(d_in[2], b1f,  H, flag);
    k_cvt<<<1, 256, 0, stream>>>(d_in[3], g1f,  H, flag);
    k_cvt<<<1, 256, 0, stream>>>(d_in[4], be1f, H, flag);
    k_cvt<<<(H*O+255)/256, 256, 0, stream>>>(d_in[5], w2f, H*O, flag);
    k_cvt<<<1, 256, 0, stream>>>(d_in[6], b2f,  O, flag);
    k_cvt<<<1, 256, 0, stream>>>(d_in[7], g2f,  O, flag);
    k_cvt<<<1, 256, 0, stream>>>(d_in[8], be2f, O, flag);
    k_cvt<<<(O*D+255)/256, 256, 0, stream>>>(d_in[9], wpf, O*D, flag);
    k_cvt<<<1, 256, 0, stream>>>(d_in[10], bpf, D, flag);

    k_prep<<<N/64, 64, 0, stream>>>(xf, nrmf);
    k_scan2 <<<32*NSPL, 256, 0, stream>>>(xf, nrmf, chunk2);
    k_vsel  <<<N/256, 256, 0, stream>>>(chunk2, vthr);
    k_zero  <<<N/256, 256, 0, stream>>>(cntb);
    k_filter<<<32*NSPL, 256, 0, stream>>>(xf, nrmf, vthr, cntb, candV, candI);
    k_select<<<N/64, 64, 0, stream>>>(xf, nrmf, cntb, candV, candI, topIdx, ewArr);

    k_deg_init<<<N/256, 256, 0, stream>>>(degD);
    k_deg_scatter<<<NE/256, 256, 0, stream>>>(topIdx, ewArr, degD);
    k_dinv<<<N/256, 256, 0, stream>>>(degD, dinv);

    k_gemm1<<<(N*H)/256, 256, 0, stream>>>(xf, w1f, h1);
    k_agg_init<H><<<(N*H)/256, 256, 0, stream>>>(h1, dinv, agg1);
    k_agg_scat<H><<<NE, H, 0, stream>>>(topIdx, ewArr, dinv, h1, agg1);
    k_post128<<<N, H, 0, stream>>>(agg1, b1f, g1f, be1f, z1);

    k_gemm2<<<(N*O)/256, 256, 0, stream>>>(z1, w2f, h2);
    k_agg_init<O><<<(N*O)/256, 256, 0, stream>>>(h2, dinv, agg2);
    k_agg_scat<O><<<NE, O, 0, stream>>>(topIdx, ewArr, dinv, h2, agg2);
    k_post64<<<N, O, 0, stream>>>(agg2, b2f, g2f, be2f, z2);

    k_proj<<<(N*D)/256, 256, 0, stream>>>(z2, wpf, bpf, z3);
    k_store<<<(N*D)/256, 256, 0, stream>>>(z3, d_out, flag);
    k_edges<<<(ETOT+255)/256, 256, 0, stream>>>(topIdx, ewArr, d_out, flag);
}

// Round 8
// 670.197 us; speedup vs baseline: 1.0643x; 1.0643x over previous
//
#include <hip/hip_runtime.h>
#include <cstdint>
#include <climits>

#define N 8192
#define D 64
#define H 128
#define O 64
#define KNB 16
#define NE (N*KNB)        // 131072
#define ETOT (NE + N)     // 139264
#define OUT0 (N*D)        // 524288
#define NSPL 32           // j-splits for scan kernels
#define JSPAN 256         // j's per split (N/NSPL)
#define JTILE 128         // j-rows staged in LDS per tile (32 KB)
#define CAP 96            // candidate buffer per query

__device__ __forceinline__ float bf2f(unsigned short u){
    union { unsigned int u; float f; } v; v.u = ((unsigned int)u) << 16; return v.f;
}
__device__ __forceinline__ unsigned short f2bf(float f){
    union { float f; unsigned int u; } v; v.f = f;
    unsigned int r = v.u + 0x7FFFu + ((v.u >> 16) & 1u);   // RNE
    return (unsigned short)(r >> 16);
}

#define PIN4(v) asm volatile("" : "+v"((v).x), "+v"((v).y), "+v"((v).z), "+v"((v).w))

// ---------------- dtype probe: 1=bf16 inputs, 0=fp32 inputs ----------------
__global__ void k_probe(const unsigned short* __restrict__ x, int* __restrict__ flag){
    __shared__ int cnt;
    if (threadIdx.x == 0) cnt = 0;
    __syncthreads();
    unsigned short u = x[2*threadIdx.x];
    int e = (u >> 7) & 0xFF;
    int ok = (u == 0) || (e >= 0x60 && e <= 0x85);
    unsigned long long m = __ballot(ok);
    if ((threadIdx.x & 63) == 0) atomicAdd(&cnt, __popcll(m));
    __syncthreads();
    if (threadIdx.x == 0) *flag = (cnt >= 128) ? 1 : 0;
}

// ---------------- generic input convert -> fp32 ----------------
__global__ void k_cvt(const void* __restrict__ src, float* __restrict__ dst,
                      int n, const int* __restrict__ flag){
    int i = blockIdx.x*256 + threadIdx.x;
    if (i >= n) return;
    if (*flag) dst[i] = bf2f(((const unsigned short*)src)[i]);
    else       dst[i] = ((const float*)src)[i];
}

// ---------------- row norms: EXACT numpy fp32 pairwise semantics ----------------
__global__ void k_prep(const float* __restrict__ xf, float* __restrict__ nrmf){
    int i = blockIdx.x*64 + threadIdx.x;
    const float* xr = xf + i*D;
    float r[8];
    #pragma unroll
    for (int q = 0; q < 8; ++q) r[q] = __fmul_rn(xr[q], xr[q]);
    #pragma unroll
    for (int b = 8; b < 64; b += 8)
        #pragma unroll
        for (int q = 0; q < 8; ++q)
            r[q] = __fadd_rn(r[q], __fmul_rn(xr[b+q], xr[b+q]));
    float s = __fadd_rn(__fadd_rn(__fadd_rn(r[0],r[1]), __fadd_rn(r[2],r[3])),
                        __fadd_rn(__fadd_rn(r[4],r[5]), __fadd_rn(r[6],r[7])));
    nrmf[i] = __fsqrt_rn(s);
}

// =====================================================================
// Two-pass exact top-k (unchanged pipeline): (A) k_scan2 keeps per-chunk
// top-2 VALUES, (B) k_vsel: v_i = 16th largest of the 64-value union
// (subset of row i's sims -> provably <= true 16th largest), (C) k_filter
// rescans with fixed threshold v_i appending exact (s,j) candidates
// (superset of true top-16), (D) k_select: exact (value desc, idx asc)
// top-16. Sim chain (bitwise-stable, operand-source independent):
//   a = fma-chain k=0..63; den = fadd(fmul(ni,nj),1e-8); s = fdiv(a,den).
//
// OPERAND SOURCING (round-5/6 post-mortem): a wave-uniform GLOBAL load in
// the j-loop makes the compiler scalarize the row into 64 SGPRs (SGPR=96,
// no room to pipeline) AND demote xi4 to VGPR_Count=40 with in-loop
// reloads; neither launch-bounds budget (r5) nor asm pins (r6) changed it
// (dur pinned at 194us, 3x the 60us FMA floor). Fix: feed the j-row from
// LDS with a wave-uniform address — hardware BROADCAST (no bank
// conflicts, no TA pressure, no SGPRs), per-lane VGPR operands for the
// FMA. This is the round-0/2 operand pattern, where the allocator
// demonstrably kept the 64-VGPR query row resident (VGPR=120-124).
// LDS traffic: 256 B/wave/j broadcast — trivial. Staging: 32 KB/tile,
// perfectly coalesced float4s, amortized over 128 j-iterations.
// =====================================================================

// ---- pass A: per-lane query, LDS-broadcast j-rows, keep chunk top-2 ----
__global__ __launch_bounds__(256, 2) void k_scan2(const float* __restrict__ xf,
                                                  const float* __restrict__ nrmf,
                                                  float* __restrict__ chunk2){
    __shared__ float sB[JTILE*64];   // 32 KB j-row tile
    __shared__ float sN[JTILE];

    int tid = threadIdx.x;
    int grp = blockIdx.x & 31;        // 32 query groups of 256
    int split = blockIdx.x >> 5;      // 32 j-splits
    int i = grp*256 + tid;
    int jbase = split*JSPAN;

    const float4* xip = (const float4*)(xf + (size_t)i*D);
    float4 xi4[16];
    #pragma unroll
    for (int c = 0; c < 16; ++c) xi4[c] = xip[c];
    #pragma unroll
    for (int c = 0; c < 16; ++c) PIN4(xi4[c]);
    float ni = nrmf[i];

    float v0 = -3.0e38f, v1 = -3.0e38f;   // chunk top-2 values

    for (int t = 0; t < JSPAN/JTILE; ++t){
        int jt = jbase + t*JTILE;
        __syncthreads();   // previous tile fully consumed
        #pragma unroll
        for (int u = 0; u < (JTILE*16)/256; ++u){
            int idx = u*256 + tid;             // float4 index within tile
            ((float4*)sB)[idx] = ((const float4*)xf)[(size_t)jt*16 + idx];
        }
        if (tid < JTILE) sN[tid] = nrmf[jt + tid];
        __syncthreads();

        for (int jj = 0; jj < JTILE; ++jj){
            int j = jt + jj;
            const float4* B4 = (const float4*)(sB + jj*64);   // uniform -> broadcast
            float nj = sN[jj];
            float a = 0.0f;
            #pragma unroll
            for (int c = 0; c < 16; ++c){
                float4 b = B4[c]; float4 xa = xi4[c];
                a = __fmaf_rn(b.x, xa.x, a);
                a = __fmaf_rn(b.y, xa.y, a);
                a = __fmaf_rn(b.z, xa.z, a);
                a = __fmaf_rn(b.w, xa.w, a);
            }
            float den = __fadd_rn(__fmul_rn(ni, nj), 1e-8f);
            float thr = v1*den;
            // conservative prefilter (margin >> fdiv rounding), exact recheck
            if (j != i && a > __fmaf_rn(fabsf(thr), -1e-6f, thr)){
                float s0 = __fdiv_rn(a, den);
                if (s0 > v1){
                    if (s0 > v0){ v1 = v0; v0 = s0; } else v1 = s0;
                }
            }
        }
    }
    chunk2[(size_t)i*64 + split*2    ] = v0;
    chunk2[(size_t)i*64 + split*2 + 1] = v1;
}

// ---- v_i = 16th largest of the 64 chunk-top-2 values (subset bound) ----
__global__ void k_vsel(const float* __restrict__ chunk2, float* __restrict__ vthr){
    int i = blockIdx.x*256 + threadIdx.x;
    const float* c = chunk2 + (size_t)i*64;
    float lv[16];
    #pragma unroll
    for (int r = 0; r < 16; ++r) lv[r] = -3.0e38f;
    for (int k = 0; k < 64; ++k){
        float s = c[k];
        if (s > lv[15]){
            lv[15] = s;
            #pragma unroll
            for (int r = 15; r > 0; --r){
                if (lv[r] > lv[r-1]){ float tv = lv[r]; lv[r] = lv[r-1]; lv[r-1] = tv; }
            }
        }
    }
    vthr[i] = lv[15];
}

__global__ void k_zero(int* __restrict__ cnt){
    int i = blockIdx.x*256 + threadIdx.x;
    if (i < N) cnt[i] = 0;
}

// ---- pass B: rescan with fixed threshold, append exact candidates ----
__global__ __launch_bounds__(256, 2) void k_filter(const float* __restrict__ xf,
                                                   const float* __restrict__ nrmf,
                                                   const float* __restrict__ vthr,
                                                   int* __restrict__ cnt,
                                                   float* __restrict__ candV,
                                                   int* __restrict__ candI){
    __shared__ float sB[JTILE*64];   // 32 KB j-row tile
    __shared__ float sN[JTILE];

    int tid = threadIdx.x;
    int grp = blockIdx.x & 31;
    int split = blockIdx.x >> 5;
    int i = grp*256 + tid;
    int jbase = split*JSPAN;

    const float4* xip = (const float4*)(xf + (size_t)i*D);
    float4 xi4[16];
    #pragma unroll
    for (int c = 0; c < 16; ++c) xi4[c] = xip[c];
    #pragma unroll
    for (int c = 0; c < 16; ++c) PIN4(xi4[c]);
    float ni = nrmf[i];
    float v = vthr[i];

    for (int t = 0; t < JSPAN/JTILE; ++t){
        int jt = jbase + t*JTILE;
        __syncthreads();
        #pragma unroll
        for (int u = 0; u < (JTILE*16)/256; ++u){
            int idx = u*256 + tid;
            ((float4*)sB)[idx] = ((const float4*)xf)[(size_t)jt*16 + idx];
        }
        if (tid < JTILE) sN[tid] = nrmf[jt + tid];
        __syncthreads();

        for (int jj = 0; jj < JTILE; ++jj){
            int j = jt + jj;
            const float4* B4 = (const float4*)(sB + jj*64);   // uniform -> broadcast
            float nj = sN[jj];
            float a = 0.0f;
            #pragma unroll
            for (int c = 0; c < 16; ++c){
                float4 b = B4[c]; float4 xa = xi4[c];
                a = __fmaf_rn(b.x, xa.x, a);
                a = __fmaf_rn(b.y, xa.y, a);
                a = __fmaf_rn(b.z, xa.z, a);
                a = __fmaf_rn(b.w, xa.w, a);
            }
            float den = __fadd_rn(__fmul_rn(ni, nj), 1e-8f);
            float tq = v*den;
            // conservative: keep every j with s >= v (den > 0 always)
            if (j != i && a >= __fmaf_rn(fabsf(tq), -1e-6f, tq)){
                float s0 = __fdiv_rn(a, den);
                if (s0 >= v){
                    int slot = atomicAdd(&cnt[i], 1);
                    if (slot < CAP){
                        candV[(size_t)i*CAP + slot] = s0;
                        candI[(size_t)i*CAP + slot] = j;
                    }
                }
            }
        }
    }
}

// ---- exact top-16 among candidates; serial exact fallback on overflow ----
__global__ __launch_bounds__(64) void k_select(const float* __restrict__ xf,
                                               const float* __restrict__ nrmf,
                                               const int* __restrict__ cnt,
                                               const float* __restrict__ candV,
                                               const int* __restrict__ candI,
                                               int* __restrict__ topIdx,
                                               float* __restrict__ ewArr){
    __shared__ float sv[64*97];   // stride 97: bank-conflict-free per-lane rows
    __shared__ int   si[64*97];
    int t = threadIdx.x;
    int i = blockIdx.x*64 + t;
    int c = cnt[i];
    bool ovf = (c > CAP);
    int cc = ovf ? 0 : c;
    for (int k = 0; k < CAP; ++k){
        bool in = (k < cc);
        sv[t*97 + k] = in ? candV[(size_t)i*CAP + k] : -3.0e38f;
        si[t*97 + k] = in ? candI[(size_t)i*CAP + k] : INT_MAX;
    }
    if (!ovf){
        // guaranteed cc >= 16 (all j with s >= v stored; >=16 such exist)
        #pragma unroll 1
        for (int sel = 0; sel < KNB; ++sel){
            float bv = -3.0e38f; int bi = INT_MAX; int bk = 0;
            for (int k = 0; k < CAP; ++k){
                float vv = sv[t*97 + k]; int id = si[t*97 + k];
                if (vv > bv || (vv == bv && id < bi)){ bv = vv; bi = id; bk = k; }
            }
            sv[t*97 + bk] = -3.0e38f;
            si[t*97 + bk] = INT_MAX;
            topIdx[i*KNB + sel] = bi;
            ewArr [i*KNB + sel] = (bv > 0.5f) ? bv : 0.0f;
        }
    } else {
        // exact serial full scan (expected never on this data; correctness net)
        const float4* xip = (const float4*)(xf + (size_t)i*D);
        float4 xi4[16];
        #pragma unroll
        for (int cc2 = 0; cc2 < 16; ++cc2) xi4[cc2] = xip[cc2];
        float ni = nrmf[i];
        float lv[16]; int li[16];
        #pragma unroll
        for (int r = 0; r < 16; ++r){ lv[r] = -3.0e38f; li[r] = INT_MAX; }
        for (int j = 0; j < N; ++j){
            if (j == i) continue;
            const float4* A = (const float4*)(xf + (size_t)j*D);
            float a = 0.0f;
            #pragma unroll
            for (int cc2 = 0; cc2 < 16; ++cc2){
                float4 b = A[cc2]; float4 xa = xi4[cc2];
                a = __fmaf_rn(b.x, xa.x, a);
                a = __fmaf_rn(b.y, xa.y, a);
                a = __fmaf_rn(b.z, xa.z, a);
                a = __fmaf_rn(b.w, xa.w, a);
            }
            float den = __fadd_rn(__fmul_rn(ni, nrmf[j]), 1e-8f);
            float s0 = __fdiv_rn(a, den);
            if (s0 > lv[15]){   // strict >: ascending j scan == idx-asc ties
                lv[15] = s0; li[15] = j;
                #pragma unroll
                for (int r = 15; r > 0; --r){
                    if (lv[r] > lv[r-1]){
                        float tv = lv[r]; lv[r] = lv[r-1]; lv[r-1] = tv;
                        int ti = li[r]; li[r] = li[r-1]; li[r-1] = ti;
                    }
                }
            }
        }
        #pragma unroll
        for (int sel = 0; sel < KNB; ++sel){
            topIdx[i*KNB + sel] = li[sel];
            ewArr [i*KNB + sel] = (lv[sel] > 0.5f) ? lv[sel] : 0.0f;
        }
    }
}

// ---------------- degree / dinv ----------------
__global__ void k_deg_init(double* __restrict__ degD){
    int j = blockIdx.x*blockDim.x + threadIdx.x;
    if (j < N) degD[j] = 2.0;
}
__global__ void k_deg_scatter(const int* __restrict__ topIdx, const float* __restrict__ ewArr,
                              double* __restrict__ degD){
    int e = blockIdx.x*blockDim.x + threadIdx.x;
    if (e < NE){
        float w = ewArr[e];
        if (w > 0.0f) atomicAdd(&degD[topIdx[e]], (double)w);
    }
}
__global__ void k_dinv(const double* __restrict__ degD, float* __restrict__ dinv){
    int j = blockIdx.x*blockDim.x + threadIdx.x;
    if (j < N) dinv[j] = (float)(1.0 / sqrt(degD[j]));
}

// ---------------- dense matmuls ----------------
__global__ void k_gemm1(const float* __restrict__ xf, const float* __restrict__ W1,
                        float* __restrict__ h1){
    int id = blockIdx.x*256 + threadIdx.x;
    int i = id >> 7; int f = id & (H-1);
    const float* xr = xf + i*D;
    float acc = 0.f;
    #pragma unroll
    for (int k = 0; k < D; ++k) acc += xr[k] * W1[k*H + f];
    h1[id] = acc;
}
__global__ void k_gemm2(const float* __restrict__ z1, const float* __restrict__ W2,
                        float* __restrict__ h2){
    int id = blockIdx.x*256 + threadIdx.x;
    int i = id >> 6; int f = id & (O-1);
    const float* zr = z1 + i*H;
    float acc = 0.f;
    #pragma unroll
    for (int k = 0; k < H; ++k) acc += zr[k] * W2[k*O + f];
    h2[id] = acc;
}
__global__ void k_proj(const float* __restrict__ z2, const float* __restrict__ Wp,
                       const float* __restrict__ bp, float* __restrict__ z3){
    int id = blockIdx.x*256 + threadIdx.x;
    int i = id >> 6; int f = id & (D-1);
    const float* zr = z2 + i*O;
    float acc = bp[f];
    #pragma unroll
    for (int k = 0; k < O; ++k) acc += zr[k] * Wp[k*D + f];
    z3[id] = acc;
}

// ---------------- GCN aggregation ----------------
template<int F>
__global__ void k_agg_init(const float* __restrict__ h, const float* __restrict__ dinv,
                           float* __restrict__ agg){
    int id = blockIdx.x*256 + threadIdx.x;
    int j = id / F;
    float dj = dinv[j];
    agg[id] = 2.f * dj * dj * h[id];
}
template<int F>
__global__ void k_agg_scat(const int* __restrict__ topIdx, const float* __restrict__ ewArr,
                           const float* __restrict__ dinv, const float* __restrict__ h,
                           float* __restrict__ agg){
    int e = blockIdx.x; int f = threadIdx.x;
    float w = ewArr[e];
    if (w == 0.f) return;
    int s = e >> 4;
    int dn = topIdx[e];
    float c = dinv[s] * w * dinv[dn];
    atomicAdd(&agg[dn*F + f], c * h[s*F + f]);
}

// ---------------- bias + relu + layernorm ----------------
__global__ void k_post128(const float* __restrict__ agg, const float* __restrict__ b,
                          const float* __restrict__ g, const float* __restrict__ be,
                          float* __restrict__ z){
    __shared__ double s2[2];
    __shared__ double s3[2];
    int i = blockIdx.x; int f = threadIdx.x;
    float v = agg[i*H + f] + b[f];
    v = v > 0.f ? v : 0.f;
    int wid = f >> 6;
    double d = (double)v;
    for (int off = 32; off > 0; off >>= 1) d += __shfl_xor(d, off);
    if ((f & 63) == 0) s2[wid] = d;
    __syncthreads();
    double mu = (s2[0] + s2[1]) * (1.0/128.0);
    double dv = (double)v - mu;
    double qq = dv * dv;
    for (int off = 32; off > 0; off >>= 1) qq += __shfl_xor(qq, off);
    if ((f & 63) == 0) s3[wid] = qq;
    __syncthreads();
    double var = (s3[0] + s3[1]) * (1.0/128.0);
    double rs = 1.0 / sqrt(var + 1e-5);
    z[i*H + f] = (float)(dv * rs * (double)g[f] + (double)be[f]);
}
__global__ void k_post64(const float* __restrict__ agg, const float* __restrict__ b,
                         const float* __restrict__ g, const float* __restrict__ be,
                         float* __restrict__ z){
    int i = blockIdx.x; int f = threadIdx.x;
    float v = agg[i*O + f] + b[f];
    v = v > 0.f ? v : 0.f;
    double d = (double)v;
    for (int off = 32; off > 0; off >>= 1) d += __shfl_xor(d, off);
    double mu = d * (1.0/64.0);
    double dv = (double)v - mu;
    double qq = dv * dv;
    for (int off = 32; off > 0; off >>= 1) qq += __shfl_xor(qq, off);
    double var = qq * (1.0/64.0);
    double rs = 1.0 / sqrt(var + 1e-5);
    z[i*O + f] = (float)(dv * rs * (double)g[f] + (double)be[f]);
}

// ---------------- output stores (flag-branched dtype) ----------------
__global__ void k_store(const float* __restrict__ z3, void* __restrict__ outp,
                        const int* __restrict__ flag){
    int i = blockIdx.x*256 + threadIdx.x;
    float v = z3[i];
    if (*flag) ((unsigned short*)outp)[i] = f2bf(v);
    else       ((float*)outp)[i] = v;
}
__global__ void k_edges(const int* __restrict__ topIdx, const float* __restrict__ ewArr,
                        void* __restrict__ outp, const int* __restrict__ flag){
    int e = blockIdx.x*256 + threadIdx.x;
    if (e >= ETOT) return;
    int s, dn; float w;
    if (e < NE){ s = e >> 4; dn = topIdx[e]; w = ewArr[e]; }
    else       { s = e - NE; dn = s;        w = 1.0f; }
    if (*flag){
        unsigned short* o = (unsigned short*)outp;
        o[OUT0 + e]          = f2bf((float)s);
        o[OUT0 + ETOT + e]   = f2bf((float)dn);
        o[OUT0 + 2*ETOT + e] = f2bf(w);
    } else {
        float* o = (float*)outp;
        o[OUT0 + e]          = (float)s;
        o[OUT0 + ETOT + e]   = (float)dn;
        o[OUT0 + 2*ETOT + e] = w;
    }
}

extern "C" void kernel_launch(void* const* d_in, const int* in_sizes, int n_in,
                              void* d_out, int out_size, void* d_ws, size_t ws_size,
                              hipStream_t stream){
    char* ws = (char*)d_ws;
    int*    flag   = (int*)   (ws + 0);
    float*  w1f    = (float*) (ws + 4096);
    float*  b1f    = (float*) (ws + 36864);
    float*  g1f    = (float*) (ws + 37376);
    float*  be1f   = (float*) (ws + 37888);
    float*  w2f    = (float*) (ws + 38400);
    float*  b2f    = (float*) (ws + 71168);
    float*  g2f    = (float*) (ws + 71424);
    float*  be2f   = (float*) (ws + 71680);
    float*  wpf    = (float*) (ws + 71936);
    float*  bpf    = (float*) (ws + 88320);
    float*  xf     = (float*) (ws + 98304);      // 2 MB          -> 2195456
    float*  nrmf   = (float*) (ws + 2195456);    // 32 KB         -> 2228224
    int*    topIdx = (int*)   (ws + 2260992);    // 512 KB        -> 2785280
    float*  ewArr  = (float*) (ws + 2785280);    // 512 KB        -> 3309568
    double* degD   = (double*)(ws + 3309568);    // 64 KB         -> 3375104
    float*  dinv   = (float*) (ws + 3375104);    // 32 KB         -> 3407872
    float*  h1     = (float*) (ws + 3407872);    // 4 MB          -> 7602176
    float*  agg1   = (float*) (ws + 7602176);    // 4 MB          -> 11796480
    float*  z1     = (float*) (ws + 11796480);   // 4 MB          -> 15990784
    float*  h2     = h1;
    float*  agg2   = agg1;
    float*  z2     = z1;
    float*  z3     = h1;

    // topk scratch overlaps h1/agg1/z1-head (all dead until k_gemm1, which
    // launches after k_select completes).
    float* chunk2 = (float*)(ws + 3407872);                  // 8192*64*4 = 2 MB
    float* vthr   = (float*)(ws + 3407872 + 2097152);        // 32 KB
    int*   cntb   = (int*)  (ws + 3407872 + 2097152 + 32768);// 32 KB
    float* candV  = (float*)(ws + 3407872 + 2097152 + 65536);            // 3 MB
    int*   candI  = (int*)  (ws + 3407872 + 2097152 + 65536 + 3145728);  // 3 MB

    k_probe<<<1, 256, 0, stream>>>((const unsigned short*)d_in[0], flag);
    k_cvt<<<(N*D+255)/256, 256, 0, stream>>>(d_in[0], xf,  N*D, flag);
    k_cvt<<<(D*H+255)/256, 256, 0, stream>>>(d_in[1], w1f, D*H, flag);
    k_cvt<<<1, 256, 0, stream>>>(d_in[2], b1f,  H, flag);
    k_cvt<<<1, 256, 0, stream>>>(d_in[3], g1f,  H, flag);
    k_cvt<<<1, 256, 0, stream>>>(d_in[4], be1f, H, flag);
    k_cvt<<<(H*O+255)/256, 256, 0, stream>>>(d_in[5], w2f, H*O, flag);
    k_cvt<<<1, 256, 0, stream>>>(d_in[6], b2f,  O, flag);
    k_cvt<<<1, 256, 0, stream>>>(d_in[7], g2f,  O, flag);
    k_cvt<<<1, 256, 0, stream>>>(d_in[8], be2f, O, flag);
    k_cvt<<<(O*D+255)/256, 256, 0, stream>>>(d_in[9], wpf, O*D, flag);
    k_cvt<<<1, 256, 0, stream>>>(d_in[10], bpf, D, flag);

    k_prep<<<N/64, 64, 0, stream>>>(xf, nrmf);
    k_scan2 <<<32*NSPL, 256, 0, stream>>>(xf, nrmf, chunk2);
    k_vsel  <<<N/256, 256, 0, stream>>>(chunk2, vthr);
    k_zero  <<<N/256, 256, 0, stream>>>(cntb);
    k_filter<<<32*NSPL, 256, 0, stream>>>(xf, nrmf, vthr, cntb, candV, candI);
    k_select<<<N/64, 64, 0, stream>>>(xf, nrmf, cntb, candV, candI, topIdx, ewArr);

    k_deg_init<<<N/256, 256, 0, stream>>>(degD);
    k_deg_scatter<<<NE/256, 256, 0, stream>>>(topIdx, ewArr, degD);
    k_dinv<<<N/256, 256, 0, stream>>>(degD, dinv);

    k_gemm1<<<(N*H)/256, 256, 0, stream>>>(xf, w1f, h1);
    k_agg_init<H><<<(N*H)/256, 256, 0, stream>>>(h1, dinv, agg1);
    k_agg_scat<H><<<NE, H, 0, stream>>>(topIdx, ewArr, dinv, h1, agg1);
    k_post128<<<N, H, 0, stream>>>(agg1, b1f, g1f, be1f, z1);

    k_gemm2<<<(N*O)/256, 256, 0, stream>>>(z1, w2f, h2);
    k_agg_init<O><<<(N*O)/256, 256, 0, stream>>>(h2, dinv, agg2);
    k_agg_scat<O><<<NE, O, 0, stream>>>(topIdx, ewArr, dinv, h2, agg2);
    k_post64<<<N, O, 0, stream>>>(agg2, b2f, g2f, be2f, z2);

    k_proj<<<(N*D)/256, 256, 0, stream>>>(z2, wpf, bpf, z3);
    k_store<<<(N*D)/256, 256, 0, stream>>>(z3, d_out, flag);
    k_edges<<<(ETOT+255)/256, 256, 0, stream>>>(topIdx, ewArr, d_out, flag);
}